// Round 9
// baseline (526.905 us; speedup 1.0000x reference)
//
#include <hip/hip_runtime.h>
#include <hip/hip_fp16.h>
#include <stdint.h>

typedef float  f32x4  __attribute__((ext_vector_type(4)));
typedef short  bf16x8 __attribute__((ext_vector_type(8)));
typedef _Float16 h2v  __attribute__((ext_vector_type(2)));

#define NEGV -10000.0f
#define LOG2E 1.442695041f

__device__ __forceinline__ unsigned short f32_to_bf16(float f){
  union { float f; uint32_t u; } v; v.f = f;
  uint32_t u = v.u;
  u += 0x7fffu + ((u >> 16) & 1u);          // RNE
  return (unsigned short)(u >> 16);
}
__device__ __forceinline__ float bf16_lo(uint32_t u){
  union { uint32_t u; float f; } v; v.u = (u & 0xffffu) << 16; return v.f;
}
__device__ __forceinline__ float bf16_hi(uint32_t u){
  union { uint32_t u; float f; } v; v.u = u & 0xffff0000u; return v.f;
}
// fast gates: exp2 + rcp (both single hw ops); saturate correctly, no NaN
__device__ __forceinline__ float fsig(float x){
  return __builtin_amdgcn_rcpf(1.0f + __builtin_exp2f(-LOG2E * x));
}
__device__ __forceinline__ float ftanh_(float x){
  return 1.0f - 2.0f * __builtin_amdgcn_rcpf(1.0f + __builtin_exp2f(2.0f * LOG2E * x));
}
// i8 weight quant, scale 512 (|w| <= 0.248 covered; clamp otherwise)
__device__ __forceinline__ uint32_t enc_i8(float x){
  int v = (int)rintf(x * 512.0f);
  v = v > 127 ? 127 : (v < -127 ? -127 : v);
  return (uint32_t)(v & 0xff);
}
// signed i8 dot4: d = a.b + c  (identical products to mfma_i32_i8)
__device__ __forceinline__ int sdot4(uint32_t a, uint32_t b, int c){
#if __has_builtin(__builtin_amdgcn_sdot4)
  return __builtin_amdgcn_sdot4((int)a, (int)b, c, false);
#else
  #pragma unroll
  for (int k = 0; k < 4; k++)
    c += (int)(signed char)((a >> (8*k)) & 0xff) *
         (int)(signed char)((b >> (8*k)) & 0xff);
  return c;
#endif
}
__device__ __forceinline__ float fdot2f(uint32_t w, uint32_t h, float acc){
#if __has_builtin(__builtin_amdgcn_fdot2)
  union { uint32_t u; h2v h; } a, b;
  a.u = w; b.u = h;
  return __builtin_amdgcn_fdot2(a.h, b.h, acc, false);
#else
  acc += __half2float(__ushort_as_half((unsigned short)(w & 0xffffu))) *
         __half2float(__ushort_as_half((unsigned short)(h & 0xffffu)));
  acc += __half2float(__ushort_as_half((unsigned short)(w >> 16))) *
         __half2float(__ushort_as_half((unsigned short)(h >> 16)));
  return acc;
#endif
}
// raw workgroup barrier: wait LDS only, do NOT drain vmcnt
__device__ __forceinline__ void wg_barrier_lds(){
  __builtin_amdgcn_s_waitcnt(0xC07F);   // lgkmcnt(0), vmcnt/expcnt untouched
  asm volatile("" ::: "memory");
  __builtin_amdgcn_s_barrier();
  asm volatile("" ::: "memory");
}
// single-wave LDS ordering fence (no barrier needed within one wave)
__device__ __forceinline__ void wave_lds_fence(){
  __builtin_amdgcn_s_waitcnt(0xC07F);   // lgkmcnt(0)
  asm volatile("" ::: "memory");
}
// pack Viterbi candidate: score (strictly negative) with predecessor index
// in low 5 mantissa bits; max() then does first-max argmax.
__device__ __forceinline__ float vpack(float sc, int p){
  const int i = (__float_as_int(sc) & 0xFFFFFFE0) | p;   // v_and_or_b32
  return __int_as_float(i);
}

// ---------------------------------------------------------------------------
// Quantize Whh_{f,b} [1024,256] f32 -> i8 (x512), rows gate-interleaved.
// ---------------------------------------------------------------------------
__global__ __launch_bounds__(256) void k_quant(
    const float* __restrict__ whh_f, const float* __restrict__ whh_b,
    uint32_t* __restrict__ wq)
{
  const int id  = blockIdx.x * 256 + threadIdx.x;   // 0..131071
  const int dir = id >> 16;
  const int rem = id & 0xffff;
  const int np  = rem >> 6;
  const int d   = rem & 63;
  const int u = np >> 2, g = np & 3;
  const float* __restrict__ w = dir ? whh_b : whh_f;
  const float4 v = *(const float4*)(w + (size_t)(g * 256 + u) * 256 + d * 4);
  wq[id] = enc_i8(v.x) | (enc_i8(v.y) << 8) | (enc_i8(v.z) << 16) | (enc_i8(v.w) << 24);
}

// ---------------------------------------------------------------------------
// XP[m][n'] = embed[sent[m]] @ Wih' ^T + b'   (bf16 MFMA, 128x128 tiles)
// ---------------------------------------------------------------------------
__global__ __launch_bounds__(256) void k_xproj(
    const int* __restrict__ sent, const float* __restrict__ embed,
    const float* __restrict__ wih_f, const float* __restrict__ wih_b,
    const float* __restrict__ bias_f, const float* __restrict__ bias_b,
    unsigned short* __restrict__ xp)
{
  __shared__ __align__(16) short At[128 * 32];
  __shared__ __align__(16) short Bt[128 * 32];
  const int bid = blockIdx.x;
  const int tm = bid >> 4;                  // 0..127  (same tm for 16 blocks)
  const int tn = bid & 15;                  // 0..15
  const int dir = tn >> 3;
  const int nloc0 = (tn & 7) * 128;
  const float* __restrict__ wsrc = dir ? wih_b : wih_f;
  const float* __restrict__ bsrc = dir ? bias_b : bias_f;

  const int tid = threadIdx.x;
  const int wv = tid >> 6;
  const int lane = tid & 63;
  const int lr = lane & 15;
  const int lq = lane >> 4;

  const int r  = tid >> 1;
  const int ch = (tid & 1) * 16;

  const int tok = sent[tm * 128 + r];
  const int nprow = nloc0 + r;
  const float* arow = embed + (size_t)tok * 256 + ch;
  const float* brow = wsrc + (size_t)((nprow & 3) * 256 + (nprow >> 2)) * 256 + ch;
  short* at_dst = At + r * 32 + ch;
  short* bt_dst = Bt + r * 32 + ch;

  f32x4 acc[2][8];
  #pragma unroll
  for (int i = 0; i < 2; i++)
    #pragma unroll
    for (int n = 0; n < 8; n++)
      acc[i][n] = (f32x4){0.f, 0.f, 0.f, 0.f};

  for (int k0 = 0; k0 < 256; k0 += 32) {
    #pragma unroll
    for (int qq = 0; qq < 4; qq++) {
      const float4 va = *(const float4*)(arow + k0 + qq * 4);
      const float4 vb = *(const float4*)(brow + k0 + qq * 4);
      short4 sa, sb;
      sa.x = (short)f32_to_bf16(va.x); sa.y = (short)f32_to_bf16(va.y);
      sa.z = (short)f32_to_bf16(va.z); sa.w = (short)f32_to_bf16(va.w);
      sb.x = (short)f32_to_bf16(vb.x); sb.y = (short)f32_to_bf16(vb.y);
      sb.z = (short)f32_to_bf16(vb.z); sb.w = (short)f32_to_bf16(vb.w);
      *(short4*)(at_dst + qq * 4) = sa;
      *(short4*)(bt_dst + qq * 4) = sb;
    }
    __syncthreads();
    bf16x8 bfr[8];
    #pragma unroll
    for (int n = 0; n < 8; n++)
      bfr[n] = *(const bf16x8*)(Bt + (n * 16 + lr) * 32 + lq * 8);
    #pragma unroll
    for (int i = 0; i < 2; i++) {
      const bf16x8 af = *(const bf16x8*)(At + (wv * 32 + i * 16 + lr) * 32 + lq * 8);
      #pragma unroll
      for (int n = 0; n < 8; n++)
        acc[i][n] = __builtin_amdgcn_mfma_f32_16x16x32_bf16(af, bfr[n], acc[i][n], 0, 0, 0);
    }
    __syncthreads();
  }
  #pragma unroll
  for (int i = 0; i < 2; i++) {
    #pragma unroll
    for (int n = 0; n < 8; n++) {
      const int nloc = nloc0 + n * 16 + lr;
      const float bias = bsrc[(nloc & 3) * 256 + (nloc >> 2)];
      #pragma unroll
      for (int rr = 0; rr < 4; rr++) {
        const int m = tm * 128 + wv * 32 + i * 16 + lq * 4 + rr;
        xp[(size_t)m * 2048 + dir * 1024 + nloc] = f32_to_bf16(acc[i][n][rr] + bias);
      }
    }
  }
}

// ---------------------------------------------------------------------------
// Persistent LSTM v7 (sdot4): 1 WG (512 thr, 8 waves) per (b,dir).
// r8 diagnosis: VGPR_Count=104 < 128 weight regs => the compiler was
// RE-LOADING all weights from L2 every step (4 MB/step/XCD ~ 930 ns/step
// == measured). Redesign: lane-pair (even: gates i,f / odd: g,o) per unit;
// weights = 128 PLAIN dwords/thread (no MFMA quad constraint -> allocator
// keeps them resident); z via v_dot4_i32_i8 (bit-identical products to the
// i8 MFMA); h broadcast from LDS in uint4 chunks; gate exchange via
// __shfl_xor(1) (DPP); ONE lgkm barrier/step.
// ---------------------------------------------------------------------------
__global__ __launch_bounds__(512, 2) void k_lstm(
    const unsigned short* __restrict__ xp, const uint32_t* __restrict__ wq,
    __half* __restrict__ hout)
{
  __shared__ __align__(16) unsigned char hbuf[2][256];
  const int bid = blockIdx.x;
  const int dir = bid & 1;
  const int b = bid >> 1;
  const int tid = threadIdx.x;
  const int w = tid >> 6;          // wave 0..7
  const int l = tid & 63;
  const int u = w * 32 + (l >> 1); // owned unit 0..255
  const int role = l & 1;          // 0: gates i,f ; 1: gates g,o

  // weights: rows 4u+2*role, 4u+2*role+1 -> 128 dwords, asm-pinned
  uint32_t w0[64], w1[64];
  {
    const uint32_t* rp = wq + dir * 65536 + (size_t)(4 * u + 2 * role) * 64;
    #pragma unroll
    for (int j = 0; j < 16; j++) {
      uint4 q0 = *(const uint4*)(rp + j * 4);
      uint4 q1 = *(const uint4*)(rp + 64 + j * 4);
      asm volatile("" : "+v"(q0.x), "+v"(q0.y), "+v"(q0.z), "+v"(q0.w),
                        "+v"(q1.x), "+v"(q1.y), "+v"(q1.z), "+v"(q1.w));
      w0[j * 4 + 0] = q0.x; w0[j * 4 + 1] = q0.y;
      w0[j * 4 + 2] = q0.z; w0[j * 4 + 3] = q0.w;
      w1[j * 4 + 0] = q1.x; w1[j * 4 + 1] = q1.y;
      w1[j * 4 + 2] = q1.z; w1[j * 4 + 3] = q1.w;
    }
  }
  if (tid < 64) ((uint32_t*)hbuf[0])[tid] = 0;   // h_{-1} = 0
  float c = 0.0f;
  // owned gate-pair xp dword: row stride 1024 dwords, offset 2u+role
  const uint32_t* xpd = (const uint32_t*)xp + (size_t)b * (256 * 1024)
                        + dir * 512 + 2 * u + role;
  __half* hb = hout + (size_t)b * (256 * 512) + dir * 256 + u;   // role 0 only

  // prefetch xp for steps 0 and 1
  uint32_t xa, xb;
  {
    const int t0 = dir ? 255 : 0;
    const int t1 = dir ? 254 : 1;
    xa = xpd[(size_t)t0 * 1024];
    xb = xpd[(size_t)t1 * 1024];
  }
  __syncthreads();   // full fence once: hbuf[0] zero visible

#define LSTM_STEP(SS, SRD, SWR, XC)                                          \
  {                                                                          \
    const int t_ = dir ? (255 - (SS)) : (SS);                                \
    const uint4* hb4 = (const uint4*)hbuf[SRD];                              \
    int a0 = 0, a1 = 0;                                                      \
    uint4 hc = hb4[0];                                                       \
    _Pragma("unroll")                                                        \
    for (int ck = 0; ck < 16; ck++) {                                        \
      const uint4 hq = hc;                                                   \
      if (ck < 15) hc = hb4[ck + 1];                                         \
      a0 = sdot4(w0[ck * 4 + 0], hq.x, a0);                                  \
      a0 = sdot4(w0[ck * 4 + 1], hq.y, a0);                                  \
      a0 = sdot4(w0[ck * 4 + 2], hq.z, a0);                                  \
      a0 = sdot4(w0[ck * 4 + 3], hq.w, a0);                                  \
      a1 = sdot4(w1[ck * 4 + 0], hq.x, a1);                                  \
      a1 = sdot4(w1[ck * 4 + 1], hq.y, a1);                                  \
      a1 = sdot4(w1[ck * 4 + 2], hq.z, a1);                                  \
      a1 = sdot4(w1[ck * 4 + 3], hq.w, a1);                                  \
    }                                                                        \
    const float SINV = 1.0f / 65536.0f;                                      \
    const float z0 = (float)a0 * SINV + bf16_lo(XC);                         \
    const float z1 = (float)a1 * SINV + bf16_hi(XC);                         \
    {  /* prefetch owned xp for step SS+2 */                                 \
      int spf = (SS) + 2; spf = spf > 255 ? 255 : spf;                       \
      const int tpf = dir ? (255 - spf) : spf;                               \
      XC = xpd[(size_t)tpf * 1024];                                          \
    }                                                                        \
    /* role 0: ga=sig(i), gb=sig(f); role 1: ga=tanh(g), gb=sig(o) */        \
    const float ga = role ? ftanh_(z0) : fsig(z0);                           \
    const float gb = fsig(z1);                                               \
    const float gg = __shfl_xor(ga, 1, 64);   /* role0 receives tanh(g) */   \
    const float og = __shfl_xor(gb, 1, 64);   /* role0 receives sig(o) */    \
    if (role == 0) {                                                         \
      c = gb * c + ga * gg;                                                  \
      const float h_ = og * ftanh_(c);                                       \
      hb[(size_t)t_ * 512] = __float2half(h_);                               \
      int hq_ = (int)rintf(h_ * 128.0f);                                     \
      hq_ = hq_ > 127 ? 127 : (hq_ < -127 ? -127 : hq_);                     \
      hbuf[SWR][u] = (unsigned char)(hq_ & 0xff);                            \
    }                                                                        \
    wg_barrier_lds();                                                        \
  }

  for (int s = 0; s < 256; s += 2) {
    LSTM_STEP(s,     0, 1, xa)
    LSTM_STEP(s + 1, 1, 0, xb)
  }
#undef LSTM_STEP
}

// ---------------------------------------------------------------------------
// feats v3: W-row chunks hoisted to registers, reused across 8 t's.
// ---------------------------------------------------------------------------
__global__ __launch_bounds__(256) void k_feats(
    const __half* __restrict__ hg, const float* __restrict__ wout,
    const float* __restrict__ bout, float* __restrict__ feats)
{
  __shared__ __align__(16) uint32_t W2[32 * 260];   // stride 260: 16B-aligned rows
  __shared__ float bo[32];
  const int b  = blockIdx.x >> 2;
  const int t0 = (blockIdx.x & 3) * 64;
  const int tid = threadIdx.x;
  #pragma unroll
  for (int i = 0; i < 32; i++) {
    const float2 v = *(const float2*)(wout + (size_t)i * 512 + tid * 2);
    const uint32_t lo = (uint32_t)__half_as_ushort(__float2half(v.x));
    const uint32_t hi = (uint32_t)__half_as_ushort(__float2half(v.y));
    W2[i * 260 + tid] = lo | (hi << 16);
  }
  if (tid < 32) bo[tid] = bout[tid];
  __syncthreads();
  const int n = tid & 31;
  const int tg = tid >> 5;
  const uint32_t* hrow0 = (const uint32_t*)(hg + (size_t)b * (256 * 512));
  float a[8];
  #pragma unroll
  for (int tt = 0; tt < 8; tt++) a[tt] = 0.0f;
  for (int ck = 0; ck < 8; ck++) {                  // 32-dword W chunk in regs
    uint4 wch[8];
    #pragma unroll
    for (int j = 0; j < 8; j++)
      wch[j] = *(const uint4*)(&W2[n * 260 + ck * 32 + j * 4]);
    #pragma unroll
    for (int tt = 0; tt < 8; tt++) {
      const int t = t0 + tg * 8 + tt;
      const uint4* hr = (const uint4*)(hrow0 + t * 256 + ck * 32);
      float acc = a[tt];
      #pragma unroll
      for (int j = 0; j < 8; j++) {
        const uint4 hq = hr[j];
        acc = fdot2f(wch[j].x, hq.x, acc);
        acc = fdot2f(wch[j].y, hq.y, acc);
        acc = fdot2f(wch[j].z, hq.z, acc);
        acc = fdot2f(wch[j].w, hq.w, acc);
      }
      a[tt] = acc;
    }
  }
  #pragma unroll
  for (int tt = 0; tt < 8; tt++) {
    const int t = t0 + tg * 8 + tt;
    feats[((size_t)b * 256 + t) * 32 + n] = bo[n] + a[tt];
  }
}

// ---------------------------------------------------------------------------
// Viterbi v5: one WG (1 wave) per b; halves split predecessors 16/16,
// packed-idx max per half, cross-half combine via __shfl_xor(32).
// ---------------------------------------------------------------------------
__global__ __launch_bounds__(64) void k_viterbi(
    const float* __restrict__ feats, const float* __restrict__ trans,
    int* __restrict__ paths, float* __restrict__ scores)
{
  __shared__ __align__(16) float vbuf[32];
  __shared__ unsigned char bp[256][32];
  __shared__ int tags[256];
  const int tid = threadIdx.x;
  const int n = tid & 31;
  const int hf = tid >> 5;                   // 0: preds 0-15, 1: preds 16-31
  const int b = blockIdx.x;
  float tcol[16];
  #pragma unroll
  for (int p = 0; p < 16; p++) tcol[p] = trans[(hf * 16 + p) * 32 + n];
  float v = (n == 0) ? -20000.0f : (NEGV - 20000.0f);
  const float* fb = feats + (size_t)b * (256 * 32) + n;
  // scalar 4-deep feats prefetch ring (manual rotation)
  float xf0 = fb[0], xf1 = fb[32], xf2 = fb[64], xf3 = fb[96];

  for (int t = 0; t < 256; t++) {
    if (hf == 0) vbuf[n] = v;
    wave_lds_fence();
    float g0, g1, g2, g3;
    #define VG(GI, DST)                                                       \
    {                                                                         \
      const float4 q4 = ((const float4*)vbuf)[hf * 4 + GI];                   \
      const int p0 = hf * 16 + GI * 4;                                        \
      const float c0 = vpack(q4.x + tcol[GI * 4 + 0], p0 + 0);                \
      const float c1 = vpack(q4.y + tcol[GI * 4 + 1], p0 + 1);                \
      const float c2 = vpack(q4.z + tcol[GI * 4 + 2], p0 + 2);                \
      const float c3 = vpack(q4.w + tcol[GI * 4 + 3], p0 + 3);                \
      DST = fmaxf(fmaxf(c0, c1), fmaxf(c2, c3));                              \
    }
    VG(0, g0) VG(1, g1) VG(2, g2) VG(3, g3)
    #undef VG
    const float hbest = fmaxf(fmaxf(g0, g1), fmaxf(g2, g3));
    const float other = __shfl_xor(hbest, 32, 64);
    const float best = fmaxf(hbest, other);
    if (hf == 0) bp[t][n] = (unsigned char)(__float_as_int(best) & 31);
    v = best + xf0;
    xf0 = xf1; xf1 = xf2; xf2 = xf3;
    {
      int tp = t + 4; tp = tp > 255 ? 255 : tp;
      xf3 = fb[(size_t)tp * 32];
    }
  }
  // terminal scores (undo the -20000 shift); lower half's tcol[0]=trans[0][n]
  if (hf == 0) vbuf[n] = v + tcol[0];
  wave_lds_fence();
  if (tid == 0) {
    float bs = vbuf[0]; int bt = 0;
    #pragma unroll 1
    for (int p = 1; p < 32; p++) {
      if (vbuf[p] > bs) { bs = vbuf[p]; bt = p; }
    }
    scores[b] = bs + 20000.0f;
    int tg = bt;
    tags[255] = tg;
    #pragma unroll 1
    for (int t = 255; t >= 1; t--) {
      tg = bp[t][tg];
      tags[t - 1] = tg;
    }
  }
  wave_lds_fence();
  #pragma unroll
  for (int i = 0; i < 4; i++) {
    const int t = i * 64 + tid;
    paths[(size_t)b * 256 + t] = tags[t];
  }
}

extern "C" void kernel_launch(void* const* d_in, const int* in_sizes, int n_in,
                              void* d_out, int out_size, void* d_ws, size_t ws_size,
                              hipStream_t stream)
{
  (void)in_sizes; (void)n_in; (void)out_size; (void)ws_size;
  const int*   sent  = (const int*)d_in[0];
  const float* embed = (const float*)d_in[1];
  const float* wih_f = (const float*)d_in[2];
  const float* whh_f = (const float*)d_in[3];
  const float* b_f   = (const float*)d_in[4];
  const float* wih_b = (const float*)d_in[5];
  const float* whh_b = (const float*)d_in[6];
  const float* b_b   = (const float*)d_in[7];
  const float* wout  = (const float*)d_in[8];
  const float* bout  = (const float*)d_in[9];
  const float* trans = (const float*)d_in[10];

  char* ws = (char*)d_ws;
  unsigned short* XP = (unsigned short*)(ws);        // 67,108,864 B  [16384][2048] bf16
  __half*   Hg = (__half*)(ws + 67108864);           // 16,777,216 B  [64][256][512] f16
  uint32_t* WQ = (uint32_t*)(ws + 83886080);         //    524,288 B  i8 Whh
  float*    FT = (float*)(ws + 84410368);            //  2,097,152 B  feats f32

  int*   paths  = (int*)d_out;                       // [64][256] int32 tags
  float* scores = (float*)d_out + 16384;             // [64] f32

  k_quant  <<<dim3(512),  dim3(256), 0, stream>>>(whh_f, whh_b, WQ);
  k_xproj  <<<dim3(2048), dim3(256), 0, stream>>>(sent, embed, wih_f, wih_b, b_f, b_b, XP);
  k_lstm   <<<dim3(128),  dim3(512), 0, stream>>>(XP, WQ, Hg);
  k_feats  <<<dim3(256),  dim3(256), 0, stream>>>(Hg, wout, bout, FT);
  k_viterbi<<<dim3(64),   dim3(64),  0, stream>>>(FT, trans, paths, scores);
}